// Round 7
// baseline (1935.177 us; speedup 1.0000x reference)
//
#include <hip/hip_runtime.h>

// OnlineLSTM: B=8192, T=2048, I=1, H=50.
// BARRIER-FREE recurrence: one wave owns 4 batch rows AND all 50 hidden
// columns, so h never crosses waves — no __syncthreads in the t-loop at all
// (R3-R6 showed runtime/step is pinned ~1700 cyc by the barrier-aligned
// serial path, independent of wave count). LDS h round-trip within a wave is
// ordered by the in-order DS pipe + compiler lgkmcnt.
// Batch rows sit at MFMA A-rows m=4b: C rows quad*4+r are valid exactly at
// r=0, so gate math is 4 full-wave gate_pair slots (28 transc/wave-step).
// Wave computes all 16 N-tiles (4 gates x 4 j-tiles): 32 MFMAs/step — MFMA
// pipe has slack (was 16% busy). B fragments persistent: 128 VGPRs.
// K padded 50->64; k=50 carries x_t, k=51 carries 1.0 so MFMA output IS the
// exp2 argument (weights prescaled by -log2e for i,f,o / +2log2e for g).
// Gate algebra: common-denominator form, 7 transcendentals per (b,j).
// Grid: 8192/4 = 2048 waves = 512 blocks(256thr) = 2 blocks/CU = 2 waves/SIMD.

#define HID   50
#define NSTEP 2048
#define RPW   4      // batch rows per wave
#define HSTR  72     // fp16 elems per h row (144 B, 16B-aligned for b128)

typedef _Float16 half8   __attribute__((ext_vector_type(8)));
typedef float    float4v __attribute__((ext_vector_type(4)));

__device__ __forceinline__ float gate_pair(float zi, float zf, float zg, float zo,
                                           float& c) {
    // zi,zf,zo = -log2e * raw;  zg = 2log2e * raw  (prescaled in weights)
    float ei = __builtin_amdgcn_exp2f(zi);   // e^{-i_raw}
    float ef = __builtin_amdgcn_exp2f(zf);
    float Eg = __builtin_amdgcn_exp2f(zg);   // e^{2 g_raw}
    float eo = __builtin_amdgcn_exp2f(zo);
    float t1  = (1.0f + ei) * (1.0f + Eg);
    float num = c * t1 + (1.0f + ef) * (Eg - 1.0f);
    float D   = t1 * (1.0f + ef);
    c = num * __builtin_amdgcn_rcpf(D);
    float a  = fminf(fmaxf(2.8853900817779268f * c, -24.0f), 24.0f);
    float Ec = __builtin_amdgcn_exp2f(a);    // e^{2c}
    return (Ec - 1.0f) * __builtin_amdgcn_rcpf((1.0f + eo) * (1.0f + Ec));
}

__global__ __launch_bounds__(256, 2) void lstm_fused(
    const float* __restrict__ x,
    const float* __restrict__ W_ih,
    const float* __restrict__ W_hh,
    const float* __restrict__ b_ih,
    const float* __restrict__ b_hh,
    const float* __restrict__ W_lin,
    const float* __restrict__ b_lin,
    float* __restrict__ out)
{
    __shared__ __align__(16) _Float16 hbuf[4][16][HSTR];  // per-wave slice

    const int tid  = threadIdx.x;
    const int wave = tid >> 6;
    const int lane = tid & 63;
    const int col  = lane & 15;
    const int quad = lane >> 4;
    const int b0   = blockIdx.x * 16 + wave * RPW;  // this wave's batch rows
    _Float16 (*hb)[HSTR] = hbuf[wave];
    const int hrow = 4 * quad;                      // LDS row for b = b0+quad

    // ---- init own slice: zeros; x_0 at [4b][50]; 1.0 at [4b][51] ----
    // (wave-private; in-order DS => no sync needed anywhere)
    for (int i = lane; i < 16 * HSTR; i += 64)
        (&hb[0][0])[i] = (_Float16)0.0f;
    if (col == 0) {
        hb[hrow][HID]     = (_Float16)x[(size_t)(b0 + quad) * NSTEP];
        hb[hrow][HID + 1] = (_Float16)1.0f;
    }

    // ---- persistent B fragments [gate][jtile][khalf], prescaled ----
    const float LOG2E = 1.4426950408889634f;
    half8 bfrag[4][4][2];
    for (int g = 0; g < 4; ++g) {
        const float sc = (g == 2) ? (2.0f * LOG2E) : (-LOG2E);
        for (int jt = 0; jt < 4; ++jt) {
            const int j = jt * 16 + col;
            for (int kt = 0; kt < 2; ++kt) {
                half8 f;
                #pragma unroll
                for (int jj = 0; jj < 8; ++jj) {
                    int k = kt * 32 + quad * 8 + jj;
                    float v = 0.0f;
                    if (j < HID) {
                        int row = g * HID + j;
                        if (k < HID)           v = W_hh[row * HID + k];
                        else if (k == HID)     v = W_ih[row];
                        else if (k == HID + 1) v = b_ih[row] + b_hh[row];
                    }
                    f[jj] = (_Float16)(v * sc);
                }
                bfrag[g][jt][kt] = f;
            }
        }
    }

    float c[4] = {0.f, 0.f, 0.f, 0.f};   // c for (b=quad, j=16*jt+col)
    const float* xrow = x + (size_t)(b0 + quad) * NSTEP;
    const float4v Z4 = {0.f, 0.f, 0.f, 0.f};

#define MFMA16(A, B, C) __builtin_amdgcn_mfma_f32_16x16x32_f16(A, B, C, 0, 0, 0)

    for (int t = 0; t < NSTEP; ++t) {
        // prefetch next x (consumed at end of this step; L1-resident lines)
        float xn = 0.f;
        if (col == 0) {
            int tt = (t + 1 < NSTEP) ? (t + 1) : (NSTEP - 1);
            xn = xrow[tt];
        }

        // A fragments: A[m=col][k=quad*8+jj (+32)] — single buffer; reads
        // precede this step's writes in program order (in-order DS).
        const _Float16* arow = &hb[col][0];
        half8 a0 = *(const half8*)(arow + quad * 8);
        half8 a1 = *(const half8*)(arow + 32 + quad * 8);

        #pragma unroll
        for (int jt = 0; jt < 4; ++jt) {
            float4v d0, d1, d2, d3;
            d0 = MFMA16(a0, bfrag[0][jt][0], Z4);
            d1 = MFMA16(a0, bfrag[1][jt][0], Z4);
            d2 = MFMA16(a0, bfrag[2][jt][0], Z4);
            d3 = MFMA16(a0, bfrag[3][jt][0], Z4);
            d0 = MFMA16(a1, bfrag[0][jt][1], d0);
            d1 = MFMA16(a1, bfrag[1][jt][1], d1);
            d2 = MFMA16(a1, bfrag[2][jt][1], d2);
            d3 = MFMA16(a1, bfrag[3][jt][1], d3);
            // valid C row: r=0 only (batch rows at m=4b) -> (b=quad, j)
            float h = gate_pair(d0[0], d1[0], d2[0], d3[0], c[jt]);
            const int j = jt * 16 + col;
            if (j < HID)
                hb[hrow][j] = (_Float16)h;   // cols 50/51 never clobbered
        }
        if (col == 0)
            hb[hrow][HID] = (_Float16)xn;
    }
#undef MFMA16

    // ---- epilogue: out[b] = h_last . W_lin + b_lin ----
    if (col == 0) {
        float s = b_lin[0];
        for (int k = 0; k < HID; ++k)
            s += (float)hb[hrow][k] * W_lin[k];
        out[b0 + quad] = s;
    }
}

extern "C" void kernel_launch(void* const* d_in, const int* in_sizes, int n_in,
                              void* d_out, int out_size, void* d_ws, size_t ws_size,
                              hipStream_t stream) {
    const float* x     = (const float*)d_in[0];
    const float* W_ih  = (const float*)d_in[1];
    const float* W_hh  = (const float*)d_in[2];
    const float* b_ih  = (const float*)d_in[3];
    const float* b_hh  = (const float*)d_in[4];
    const float* W_lin = (const float*)d_in[5];
    const float* b_lin = (const float*)d_in[6];
    float* outp = (float*)d_out;
    dim3 grid(8192 / 16), block(256);   // 4 waves/block, 4 rows/wave
    hipLaunchKernelGGL(lstm_fused, grid, block, 0, stream,
                       x, W_ih, W_hh, b_ih, b_hh, W_lin, b_lin, outp);
}